// Round 8
// baseline (286.092 us; speedup 1.0000x reference)
//
#include <hip/hip_runtime.h>
#include <hip/hip_bf16.h>
#include <stdint.h>

// Problem dims
#define B_DIM 16
#define L_DIM 512
#define DM    1024
#define DF    4096

typedef __attribute__((ext_vector_type(8))) __bf16 bf16x8;
typedef __attribute__((ext_vector_type(4))) float  f32x4;

#define GLOBAL_AS __attribute__((address_space(1)))
#define LDS_AS    __attribute__((address_space(3)))

__device__ __forceinline__ unsigned short f2bf(float f){
    unsigned u = __float_as_uint(f);
    u += 0x7fffu + ((u >> 16) & 1u);      // RNE
    return (unsigned short)(u >> 16);
}

__device__ __forceinline__ void gll16(const void* g, void* l){
    __builtin_amdgcn_global_load_lds((const GLOBAL_AS uint32_t*)g,
                                     (LDS_AS uint32_t*)l, 16, 0, 0);
}

struct us4 { unsigned short x, y, z, w; };

// ================= P1: [psum (128 blocks)] ∪ [w0t (4096 blocks)] =================
__global__ void __launch_bounds__(256)
k_p1(const float* __restrict__ x, const float* __restrict__ W0,
     float* __restrict__ P, unsigned short* __restrict__ W0T){
    __shared__ float tile[32][33];
    int blk = blockIdx.x, tid = threadIdx.x;
    if (blk < 128){
        int b = blk >> 3, c = blk & 7;
        const float4* x4 = (const float4*)x;
        size_t base = ((size_t)(b*L_DIM) + c*64)*256 + tid;
        float4 acc = {0.f, 0.f, 0.f, 0.f};
        #pragma unroll 8
        for (int j = 0; j < 64; ++j){
            float4 v = x4[base + (size_t)j*256];
            acc.x += v.x; acc.y += v.y; acc.z += v.z; acc.w += v.w;
        }
        ((float4*)P)[((size_t)(b*8) + c)*256 + tid] = acc;
    } else {
        int wb = blk - 128;                   // 4096 blocks: 32 k-tiles x 128 n-tiles
        int k0 = (wb & 31) * 32, n0 = (wb >> 5) * 32;
        int tc = tid & 31, tr = tid >> 5;
        #pragma unroll
        for (int p = 0; p < 4; ++p){
            int k = tr + p*8;
            tile[k][tc] = W0[(size_t)(k0 + k)*DF + n0 + tc];
        }
        __syncthreads();
        #pragma unroll
        for (int p = 0; p < 4; ++p){
            int n = tr + p*8;
            W0T[(size_t)(n0 + n)*DM + k0 + tc] = f2bf(tile[tc][n]);
        }
    }
}

// ============ P2: [scanP (16)] ∪ [w1t (512)] ∪ [gzero (1)] ∪ [g2zero (1)] ============
__global__ void __launch_bounds__(256)
k_p2(const float* __restrict__ W1, float* __restrict__ P,
     float* __restrict__ W1T, float* __restrict__ gv, float* __restrict__ gv2){
    __shared__ float tile[32][33];
    int blk = blockIdx.x, tid = threadIdx.x;
    if (blk < 16){
        int b = blk;
        float4* P4 = (float4*)P;
        float4 run = {0.f, 0.f, 0.f, 0.f};
        #pragma unroll
        for (int c = 0; c < 8; ++c){
            size_t idx = ((size_t)(b*8) + c)*256 + tid;
            float4 v = P4[idx];
            P4[idx] = run;
            run.x += v.x; run.y += v.y; run.z += v.z; run.w += v.w;
        }
    } else if (blk < 528){
        int wb = blk - 16;                    // 512 blocks: 16 i-tiles x 32 d-tiles
        int i0 = (wb & 15) * 32, d0 = (wb >> 4) * 32;
        int tc = tid & 31, tr = tid >> 5;
        #pragma unroll
        for (int p = 0; p < 4; ++p){
            int dl = tr + p*8;
            tile[dl][tc] = W1[(size_t)(d0 + dl)*L_DIM + i0 + tc];
        }
        __syncthreads();
        #pragma unroll
        for (int p = 0; p < 4; ++p){
            int il = tr + p*8;
            W1T[(size_t)(i0 + il)*DM + d0 + tc] = tile[tc][il];
        }
    } else {
        float4 z = {0.f, 0.f, 0.f, 0.f};
        float4* g4 = (float4*)(blk == 528 ? gv : gv2);   // 8192 floats each
        #pragma unroll
        for (int k = 0; k < 8; ++k) g4[k*256 + tid] = z;
    }
}

// ================= P3: csum — S = bf16(prefix + local cumsum) =================
__global__ void __launch_bounds__(256)
k_p3(const float* __restrict__ x, const float* __restrict__ P,
     unsigned short* __restrict__ S){
    int blk = blockIdx.x, tid = threadIdx.x;  // 128 blocks
    int b = blk >> 3, c = blk & 7;
    const float4* x4 = (const float4*)x;
    us4* S4 = (us4*)S;
    size_t base = ((size_t)(b*L_DIM) + c*64)*256 + tid;
    float4 acc = ((const float4*)P)[((size_t)(b*8) + c)*256 + tid];
    #pragma unroll 4
    for (int j = 0; j < 64; ++j){
        float4 v = x4[base + (size_t)j*256];
        acc.x += v.x; acc.y += v.y; acc.z += v.z; acc.w += v.w;
        us4 o; o.x = f2bf(acc.x); o.y = f2bf(acc.y); o.z = f2bf(acc.z); o.w = f2bf(acc.w);
        S4[base + (size_t)j*256] = o;
    }
}

// ---------- CONTROL GEMM (verified on HW round 3): feeds the real output ----------
__global__ void __launch_bounds__(256)
k_gemm(const unsigned short* __restrict__ S, const unsigned short* __restrict__ W0T,
       float* __restrict__ g){
    __shared__ __bf16 As[128*32];
    __shared__ __bf16 Bs[128*32];
    const int tid  = threadIdx.x;
    const int w    = tid >> 6, lane = tid & 63;
    const int wr   = w >> 1,  wc   = w & 1;
    const int lr   = lane & 15, lh = lane >> 4;
    const int row0 = blockIdx.y * 128;
    const int n0   = blockIdx.x * 128;

    f32x4 acc[4][4] = {};
    for (int kt = 0; kt < DM; kt += 32){
        __syncthreads();
        #pragma unroll
        for (int s = 0; s < 2; ++s){
            int ch = s*256 + tid;
            gll16(S   + ((size_t)(row0 + (ch >> 2))*DM + kt + (ch & 3)*8),
                  (void*)(As + (s*256 + w*64)*8));
            gll16(W0T + ((size_t)(n0   + (ch >> 2))*DM + kt + (ch & 3)*8),
                  (void*)(Bs + (s*256 + w*64)*8));
        }
        __syncthreads();
        bf16x8 af[4], bf[4];
        #pragma unroll
        for (int mi = 0; mi < 4; ++mi)
            af[mi] = *(const bf16x8*)(As + (wr*64 + mi*16 + lr)*32 + lh*8);
        #pragma unroll
        for (int ni = 0; ni < 4; ++ni)
            bf[ni] = *(const bf16x8*)(Bs + (wc*64 + ni*16 + lr)*32 + lh*8);
        #pragma unroll
        for (int mi = 0; mi < 4; ++mi)
            #pragma unroll
            for (int ni = 0; ni < 4; ++ni)
                acc[mi][ni] = __builtin_amdgcn_mfma_f32_16x16x32_bf16(
                                  af[mi], bf[ni], acc[mi][ni], 0, 0, 0);
    }

    #pragma unroll
    for (int mi = 0; mi < 4; ++mi){
        float v[4] = {0.f, 0.f, 0.f, 0.f};
        #pragma unroll
        for (int ni = 0; ni < 4; ++ni)
            #pragma unroll
            for (int r = 0; r < 4; ++r)
                v[r] += fmaxf(acc[mi][ni][r], 0.f);
        #pragma unroll
        for (int off = 1; off < 16; off <<= 1)
            #pragma unroll
            for (int r = 0; r < 4; ++r)
                v[r] += __shfl_xor(v[r], off, 64);
        if (lr == 0){
            int row = row0 + wr*64 + mi*16 + lh*4;
            #pragma unroll
            for (int r = 0; r < 4; ++r)
                atomicAdd(&g[row + r], v[r]);
        }
    }
}

// ---------- EXPERIMENTAL GEMM: 256x256 tile, BK=64, 8 waves, 4-phase/K-tile ----------
// dbuf LDS (race-free: stage targets buffer nobody reads this iteration),
// T2 read-swizzle (slot ^= row&7) with inverse-swizzled global source,
// T5 setprio around MFMA clusters, per-phase s_barrier, boundary __syncthreads.
// Writes gv2 (scratch) only — shadow experiment, output does not depend on it.
__global__ void __launch_bounds__(512, 2)
k_gemm8(const unsigned short* __restrict__ S, const unsigned short* __restrict__ W0T,
        float* __restrict__ g2){
    __shared__ __bf16 lds[2][2][256*64];   // [buf][A=0/B=1][row*64+k] : 128 KiB
    const int tid = threadIdx.x, w = tid >> 6, lane = tid & 63;
    const int wr  = w >> 2, wc = w & 3;          // 2 x 4 waves
    const int lr  = lane & 15, lh = lane >> 4;
    const int wg  = blockIdx.x;                  // 512 = 32 m-panels x 16 n-panels
    const int swz = (wg & 7)*64 + (wg >> 3);     // XCD-chunked (512 % 8 == 0: bijective)
    const int row0 = (swz >> 4) * 256;
    const int col0 = (swz & 15) * 256;

    // stage chunk-set s (0..3) of K-tile kt into buf: linear LDS dest,
    // inverse-swizzled global source (rule #21: both-sides-or-neither).
    auto stageA = [&](int buf, int kt, int s){
        int c = s*512 + tid, row = c >> 3, p = c & 7;
        gll16(S + (size_t)(row0 + row)*DM + kt*64 + ((p ^ (row & 7)) << 3),
              (void*)(&lds[buf][0][0] + (size_t)c*8));
    };
    auto stageB = [&](int buf, int kt, int s){
        int c = s*512 + tid, row = c >> 3, p = c & 7;
        gll16(W0T + (size_t)(col0 + row)*DM + kt*64 + ((p ^ (row & 7)) << 3),
              (void*)(&lds[buf][1][0] + (size_t)c*8));
    };

    f32x4 acc[8][4] = {};
    bf16x8 af[4][2], bf[2][2];

    #pragma unroll
    for (int s = 0; s < 4; ++s){ stageA(0, 0, s); stageB(0, 0, s); }
    __syncthreads();

#define PH(QR, QC, RA, RB, SET)                                                   \
    if (RA){                                                                      \
        _Pragma("unroll") for (int mi = 0; mi < 4; ++mi)                          \
        _Pragma("unroll") for (int ks = 0; ks < 2; ++ks){                         \
            int rw = wr*128 + (QR)*64 + mi*16 + lr;                               \
            af[mi][ks] = *(const bf16x8*)(Ab + rw*64 + (((ks*4 + lh) ^ (rw & 7)) << 3)); \
        }                                                                         \
    }                                                                             \
    if (RB){                                                                      \
        _Pragma("unroll") for (int ni = 0; ni < 2; ++ni)                          \
        _Pragma("unroll") for (int ks = 0; ks < 2; ++ks){                         \
            int rb = wc*64 + (QC)*32 + ni*16 + lr;                                \
            bf[ni][ks] = *(const bf16x8*)(Bb + rb*64 + (((ks*4 + lh) ^ (rb & 7)) << 3)); \
        }                                                                         \
    }                                                                             \
    if (kt < 15){ stageA(nbuf, kt + 1, SET); stageB(nbuf, kt + 1, SET); }         \
    __builtin_amdgcn_s_barrier();                                                 \
    __builtin_amdgcn_s_setprio(1);                                                \
    _Pragma("unroll") for (int mi = 0; mi < 4; ++mi)                              \
    _Pragma("unroll") for (int ni = 0; ni < 2; ++ni)                              \
    _Pragma("unroll") for (int ks = 0; ks < 2; ++ks)                              \
        acc[(QR)*4 + mi][(QC)*2 + ni] = __builtin_amdgcn_mfma_f32_16x16x32_bf16(  \
            af[mi][ks], bf[ni][ks], acc[(QR)*4 + mi][(QC)*2 + ni], 0, 0, 0);      \
    __builtin_amdgcn_s_setprio(0);                                                \
    __builtin_amdgcn_s_barrier();

    for (int kt = 0; kt < 16; ++kt){
        const int buf = kt & 1, nbuf = buf ^ 1;
        const __bf16* Ab = &lds[buf][0][0];
        const __bf16* Bb = &lds[buf][1][0];
        PH(0, 0, 1, 1, 0)
        PH(0, 1, 0, 1, 1)
        PH(1, 1, 1, 0, 2)
        PH(1, 0, 0, 1, 3)
        __syncthreads();   // drain stage loads (vmcnt) for nbuf before next K-tile
    }
#undef PH

    // relu + row-sum over wave's 64 cols, 16-lane reduce, atomic add
    #pragma unroll
    for (int q = 0; q < 8; ++q){
        float v[4] = {0.f, 0.f, 0.f, 0.f};
        #pragma unroll
        for (int n = 0; n < 4; ++n)
            #pragma unroll
            for (int r = 0; r < 4; ++r)
                v[r] += fmaxf(acc[q][n][r], 0.f);
        #pragma unroll
        for (int off = 1; off < 16; off <<= 1)
            #pragma unroll
            for (int r = 0; r < 4; ++r)
                v[r] += __shfl_xor(v[r], off, 64);
        if (lr == 0){
            int row = row0 + wr*128 + (q >> 2)*64 + (q & 3)*16 + lh*4;
            #pragma unroll
            for (int r = 0; r < 4; ++r)
                atomicAdd(&g2[row + r], v[r]);
        }
    }
}

// ---------- comparator: duration encodes gv2 correctness (spin if mismatch) ----------
__global__ void __launch_bounds__(512)
k_cmp(const float* __restrict__ a, const float* __restrict__ b,
      float* __restrict__ sink){
    int i = blockIdx.x*512 + threadIdx.x;     // grid 16 -> 8192
    float va = a[i], vb = b[i];
    if (fabsf(va - vb) > 0.01f*fabsf(va) + 1.0f){
        float z = vb;
        for (int it = 0; it < 400000; ++it) z = fmaf(z, 1.0000001f, 1e-7f);
        if (z == 123.456f) sink[i & 63] = z;  // never true; keeps loop alive
    }
}

// ================= P5: out[b,i,:] = (sum_{j<=i} g[b,j]) * W1T[i,:] =================
__global__ void __launch_bounds__(256)
k_out(const float* __restrict__ g, const float* __restrict__ W1T,
      float* __restrict__ out){
    __shared__ float wsum[4];
    int blk = blockIdx.x, tid = threadIdx.x;
    int b = blk >> 9, i = blk & 511;
    const float* gb = g + b*512;
    float v = (tid <= i ? gb[tid] : 0.f) + (tid + 256 <= i ? gb[tid + 256] : 0.f);
    #pragma unroll
    for (int off = 32; off >= 1; off >>= 1) v += __shfl_xor(v, off, 64);
    if ((tid & 63) == 0) wsum[tid >> 6] = v;
    __syncthreads();
    float t = wsum[0] + wsum[1] + wsum[2] + wsum[3];
    float4 wv = ((const float4*)(W1T + (size_t)i*DM))[tid];
    float4 o = {t*wv.x, t*wv.y, t*wv.z, t*wv.w};
    ((float4*)(out + ((size_t)(b*512 + i))*DM))[tid] = o;
}

extern "C" void kernel_launch(void* const* d_in, const int* in_sizes, int n_in,
                              void* d_out, int out_size, void* d_ws, size_t ws_size,
                              hipStream_t stream){
    const float* x  = (const float*)d_in[0];
    const float* W0 = (const float*)d_in[1];
    const float* W1 = (const float*)d_in[2];
    float* out = (float*)d_out;

    char* ws = (char*)d_ws;
    unsigned short* W0T = (unsigned short*)ws;                        // 8 MB
    unsigned short* S   = (unsigned short*)(ws + (8u<<20));           // 16 MB
    float* P    = (float*)(ws + (24u<<20));                           // 512 KB
    float* gv   = (float*)(ws + (24u<<20) + (512u<<10));              // 32 KB
    float* gv2  = (float*)(ws + (24u<<20) + (576u<<10));              // 32 KB
    float* sink = (float*)(ws + (24u<<20) + (640u<<10));              // tiny
    float* W1T  = (float*)(ws + (25u<<20));                           // 2 MB

    k_p1   <<<4224, 256, 0, stream>>>(x, W0, P, W0T);       // psum ∪ w0t
    k_p2   <<<530,  256, 0, stream>>>(W1, P, W1T, gv, gv2); // scanP ∪ w1t ∪ zeros
    k_p3   <<<128,  256, 0, stream>>>(x, P, S);             // csum -> S (bf16)
    k_gemm <<<dim3(32,64), 256, 0, stream>>>(S, W0T, gv);   // control (output path)
    k_gemm8<<<512, 512, 0, stream>>>(S, W0T, gv2);          // shadow experiment
    k_cmp  <<<16, 512, 0, stream>>>(gv, gv2, sink);         // dur encodes verdict
    k_out  <<<8192, 256, 0, stream>>>(gv, W1T, out);        // t-reduce + scale
}

// Round 10
// 196.014 us; speedup vs baseline: 1.4596x; 1.4596x over previous
//
#include <hip/hip_runtime.h>
#include <hip/hip_bf16.h>
#include <stdint.h>

// Problem dims
#define B_DIM 16
#define L_DIM 512
#define DM    1024
#define DF    4096

typedef __attribute__((ext_vector_type(8))) __bf16 bf16x8;
typedef __attribute__((ext_vector_type(4))) float  f32x4;

#define GLOBAL_AS __attribute__((address_space(1)))
#define LDS_AS    __attribute__((address_space(3)))

__device__ __forceinline__ unsigned short f2bf(float f){
    unsigned u = __float_as_uint(f);
    u += 0x7fffu + ((u >> 16) & 1u);      // RNE
    return (unsigned short)(u >> 16);
}

__device__ __forceinline__ void gll16(const void* g, void* l){
    __builtin_amdgcn_global_load_lds((const GLOBAL_AS uint32_t*)g,
                                     (LDS_AS uint32_t*)l, 16, 0, 0);
}

struct us4 { unsigned short x, y, z, w; };

// ================= P1: [psum (128 blocks)] ∪ [w0t (4096 blocks)] =================
__global__ void __launch_bounds__(256)
k_p1(const float* __restrict__ x, const float* __restrict__ W0,
     float* __restrict__ P, unsigned short* __restrict__ W0T){
    __shared__ float tile[32][33];
    int blk = blockIdx.x, tid = threadIdx.x;
    if (blk < 128){
        int b = blk >> 3, c = blk & 7;
        const float4* x4 = (const float4*)x;
        size_t base = ((size_t)(b*L_DIM) + c*64)*256 + tid;
        float4 acc = {0.f, 0.f, 0.f, 0.f};
        #pragma unroll 8
        for (int j = 0; j < 64; ++j){
            float4 v = x4[base + (size_t)j*256];
            acc.x += v.x; acc.y += v.y; acc.z += v.z; acc.w += v.w;
        }
        ((float4*)P)[((size_t)(b*8) + c)*256 + tid] = acc;
    } else {
        int wb = blk - 128;                   // 4096 blocks: 32 k-tiles x 128 n-tiles
        int k0 = (wb & 31) * 32, n0 = (wb >> 5) * 32;
        int tc = tid & 31, tr = tid >> 5;
        #pragma unroll
        for (int p = 0; p < 4; ++p){
            int k = tr + p*8;
            tile[k][tc] = W0[(size_t)(k0 + k)*DF + n0 + tc];
        }
        __syncthreads();
        #pragma unroll
        for (int p = 0; p < 4; ++p){
            int n = tr + p*8;
            W0T[(size_t)(n0 + n)*DM + k0 + tc] = f2bf(tile[tc][n]);
        }
    }
}

// ============ P2: [scanP (16)] ∪ [w1t (512)] ∪ [gzero (1)] ============
__global__ void __launch_bounds__(256)
k_p2(const float* __restrict__ W1, float* __restrict__ P,
     float* __restrict__ W1T, float* __restrict__ gv){
    __shared__ float tile[32][33];
    int blk = blockIdx.x, tid = threadIdx.x;
    if (blk < 16){
        int b = blk;
        float4* P4 = (float4*)P;
        float4 run = {0.f, 0.f, 0.f, 0.f};
        #pragma unroll
        for (int c = 0; c < 8; ++c){
            size_t idx = ((size_t)(b*8) + c)*256 + tid;
            float4 v = P4[idx];
            P4[idx] = run;
            run.x += v.x; run.y += v.y; run.z += v.z; run.w += v.w;
        }
    } else if (blk < 528){
        int wb = blk - 16;                    // 512 blocks: 16 i-tiles x 32 d-tiles
        int i0 = (wb & 15) * 32, d0 = (wb >> 4) * 32;
        int tc = tid & 31, tr = tid >> 5;
        #pragma unroll
        for (int p = 0; p < 4; ++p){
            int dl = tr + p*8;
            tile[dl][tc] = W1[(size_t)(d0 + dl)*L_DIM + i0 + tc];
        }
        __syncthreads();
        #pragma unroll
        for (int p = 0; p < 4; ++p){
            int il = tr + p*8;
            W1T[(size_t)(i0 + il)*DM + d0 + tc] = tile[tc][il];
        }
    } else {
        float4 z = {0.f, 0.f, 0.f, 0.f};
        float4* g4 = (float4*)gv;             // 8192 floats
        #pragma unroll
        for (int k = 0; k < 8; ++k) g4[k*256 + tid] = z;
    }
}

// ================= P3: csum — S = bf16(prefix + local cumsum) =================
__global__ void __launch_bounds__(256)
k_p3(const float* __restrict__ x, const float* __restrict__ P,
     unsigned short* __restrict__ S){
    int blk = blockIdx.x, tid = threadIdx.x;  // 128 blocks
    int b = blk >> 3, c = blk & 7;
    const float4* x4 = (const float4*)x;
    us4* S4 = (us4*)S;
    size_t base = ((size_t)(b*L_DIM) + c*64)*256 + tid;
    float4 acc = ((const float4*)P)[((size_t)(b*8) + c)*256 + tid];
    #pragma unroll 4
    for (int j = 0; j < 64; ++j){
        float4 v = x4[base + (size_t)j*256];
        acc.x += v.x; acc.y += v.y; acc.z += v.z; acc.w += v.w;
        us4 o; o.x = f2bf(acc.x); o.y = f2bf(acc.y); o.z = f2bf(acc.z); o.w = f2bf(acc.w);
        S4[base + (size_t)j*256] = o;
    }
}

// ---------- GEMM (promoted, HW-validated vs control in round 8 via k_cmp) ----------
// 256x256 tile, BK=64, 8 waves (2x4), 4-phase/K-tile, dbuf LDS, T2 swizzle
// (inverse-swizzled global source + swizzled ds_read, rule #21), T5 setprio.
__global__ void __launch_bounds__(512, 2)
k_gemm8(const unsigned short* __restrict__ S, const unsigned short* __restrict__ W0T,
        float* __restrict__ g2){
    __shared__ __bf16 lds[2][2][256*64];   // [buf][A=0/B=1][row*64+k] : 128 KiB
    const int tid = threadIdx.x, w = tid >> 6, lane = tid & 63;
    const int wr  = w >> 2, wc = w & 3;          // 2 x 4 waves
    const int lr  = lane & 15, lh = lane >> 4;
    const int wg  = blockIdx.x;                  // 512 = 32 m-panels x 16 n-panels
    const int swz = (wg & 7)*64 + (wg >> 3);     // XCD-chunked (512 % 8 == 0: bijective)
    const int row0 = (swz >> 4) * 256;
    const int col0 = (swz & 15) * 256;

    auto stageA = [&](int buf, int kt, int s){
        int c = s*512 + tid, row = c >> 3, p = c & 7;
        gll16(S + (size_t)(row0 + row)*DM + kt*64 + ((p ^ (row & 7)) << 3),
              (void*)(&lds[buf][0][0] + (size_t)c*8));
    };
    auto stageB = [&](int buf, int kt, int s){
        int c = s*512 + tid, row = c >> 3, p = c & 7;
        gll16(W0T + (size_t)(col0 + row)*DM + kt*64 + ((p ^ (row & 7)) << 3),
              (void*)(&lds[buf][1][0] + (size_t)c*8));
    };

    f32x4 acc[8][4] = {};
    bf16x8 af[4][2], bf[2][2];

    #pragma unroll
    for (int s = 0; s < 4; ++s){ stageA(0, 0, s); stageB(0, 0, s); }
    __syncthreads();

#define PH(QR, QC, RA, RB, SET)                                                   \
    if (RA){                                                                      \
        _Pragma("unroll") for (int mi = 0; mi < 4; ++mi)                          \
        _Pragma("unroll") for (int ks = 0; ks < 2; ++ks){                         \
            int rw = wr*128 + (QR)*64 + mi*16 + lr;                               \
            af[mi][ks] = *(const bf16x8*)(Ab + rw*64 + (((ks*4 + lh) ^ (rw & 7)) << 3)); \
        }                                                                         \
    }                                                                             \
    if (RB){                                                                      \
        _Pragma("unroll") for (int ni = 0; ni < 2; ++ni)                          \
        _Pragma("unroll") for (int ks = 0; ks < 2; ++ks){                         \
            int rb = wc*64 + (QC)*32 + ni*16 + lr;                                \
            bf[ni][ks] = *(const bf16x8*)(Bb + rb*64 + (((ks*4 + lh) ^ (rb & 7)) << 3)); \
        }                                                                         \
    }                                                                             \
    if (kt < 15){ stageA(nbuf, kt + 1, SET); stageB(nbuf, kt + 1, SET); }         \
    __builtin_amdgcn_s_barrier();                                                 \
    __builtin_amdgcn_s_setprio(1);                                                \
    _Pragma("unroll") for (int mi = 0; mi < 4; ++mi)                              \
    _Pragma("unroll") for (int ni = 0; ni < 2; ++ni)                              \
    _Pragma("unroll") for (int ks = 0; ks < 2; ++ks)                              \
        acc[(QR)*4 + mi][(QC)*2 + ni] = __builtin_amdgcn_mfma_f32_16x16x32_bf16(  \
            af[mi][ks], bf[ni][ks], acc[(QR)*4 + mi][(QC)*2 + ni], 0, 0, 0);      \
    __builtin_amdgcn_s_setprio(0);                                                \
    __builtin_amdgcn_s_barrier();

    for (int kt = 0; kt < 16; ++kt){
        const int buf = kt & 1, nbuf = buf ^ 1;
        const __bf16* Ab = &lds[buf][0][0];
        const __bf16* Bb = &lds[buf][1][0];
        PH(0, 0, 1, 1, 0)
        PH(0, 1, 0, 1, 1)
        PH(1, 1, 1, 0, 2)
        PH(1, 0, 0, 1, 3)
        __syncthreads();   // drain stage loads (vmcnt) for nbuf before next K-tile
    }
#undef PH

    // relu + row-sum over wave's 64 cols, 16-lane reduce, atomic add
    #pragma unroll
    for (int q = 0; q < 8; ++q){
        float v[4] = {0.f, 0.f, 0.f, 0.f};
        #pragma unroll
        for (int n = 0; n < 4; ++n)
            #pragma unroll
            for (int r = 0; r < 4; ++r)
                v[r] += fmaxf(acc[q][n][r], 0.f);
        #pragma unroll
        for (int off = 1; off < 16; off <<= 1)
            #pragma unroll
            for (int r = 0; r < 4; ++r)
                v[r] += __shfl_xor(v[r], off, 64);
        if (lr == 0){
            int row = row0 + wr*128 + (q >> 2)*64 + (q & 3)*16 + lh*4;
            #pragma unroll
            for (int r = 0; r < 4; ++r)
                atomicAdd(&g2[row + r], v[r]);
        }
    }
}

// ================= P5: out[b,i,:] = (sum_{j<=i} g[b,j]) * W1T[i,:] =================
__global__ void __launch_bounds__(256)
k_out(const float* __restrict__ g, const float* __restrict__ W1T,
      float* __restrict__ out){
    __shared__ float wsum[4];
    int blk = blockIdx.x, tid = threadIdx.x;
    int b = blk >> 9, i = blk & 511;
    const float* gb = g + b*512;
    float v = (tid <= i ? gb[tid] : 0.f) + (tid + 256 <= i ? gb[tid + 256] : 0.f);
    #pragma unroll
    for (int off = 32; off >= 1; off >>= 1) v += __shfl_xor(v, off, 64);
    if ((tid & 63) == 0) wsum[tid >> 6] = v;
    __syncthreads();
    float t = wsum[0] + wsum[1] + wsum[2] + wsum[3];
    float4 wv = ((const float4*)(W1T + (size_t)i*DM))[tid];
    float4 o = {t*wv.x, t*wv.y, t*wv.z, t*wv.w};
    ((float4*)(out + ((size_t)(b*512 + i))*DM))[tid] = o;
}

extern "C" void kernel_launch(void* const* d_in, const int* in_sizes, int n_in,
                              void* d_out, int out_size, void* d_ws, size_t ws_size,
                              hipStream_t stream){
    const float* x  = (const float*)d_in[0];
    const float* W0 = (const float*)d_in[1];
    const float* W1 = (const float*)d_in[2];
    float* out = (float*)d_out;

    char* ws = (char*)d_ws;
    unsigned short* W0T = (unsigned short*)ws;                        // 8 MB
    unsigned short* S   = (unsigned short*)(ws + (8u<<20));           // 16 MB
    float* P    = (float*)(ws + (24u<<20));                           // 512 KB
    float* gv   = (float*)(ws + (24u<<20) + (512u<<10));              // 32 KB
    float* W1T  = (float*)(ws + (25u<<20));                           // 2 MB

    k_p1   <<<4224, 256, 0, stream>>>(x, W0, P, W0T);   // psum ∪ w0t
    k_p2   <<<529,  256, 0, stream>>>(W1, P, W1T, gv);  // scanP ∪ w1t ∪ gzero
    k_p3   <<<128,  256, 0, stream>>>(x, P, S);         // csum -> S (bf16)
    k_gemm8<<<512, 512, 0, stream>>>(S, W0T, gv);       // promoted GEMM
    k_out  <<<8192, 256, 0, stream>>>(gv, W1T, out);    // t-reduce + scale
}